// Round 1
// baseline (599.736 us; speedup 1.0000x reference)
//
#include <hip/hip_runtime.h>
#include <hip/hip_fp16.h>

#define HS 1024
#define TT 2048

typedef _Float16 half8 __attribute__((ext_vector_type(8)));
typedef float floatx4 __attribute__((ext_vector_type(4)));

// Async global->LDS DMA, 16B per lane. LDS dest = wave-uniform base + lane*16.
__device__ __forceinline__ void dma16(const _Float16* g, _Float16* l) {
    __builtin_amdgcn_global_load_lds(
        (const __attribute__((address_space(1))) unsigned int*)g,
        (__attribute__((address_space(3))) unsigned int*)l, 16, 0, 0);
}

// K1: dproj[n*1024+a] = bias[a] + sum_e h_dec[n,e]*W[a,e]. One wave per (n,a).
__global__ __launch_bounds__(256) void k_dproj(const float* __restrict__ h_dec,
                                               const float* __restrict__ W,
                                               const float* __restrict__ bias,
                                               float* __restrict__ dproj) {
    int wid = blockIdx.x * 4 + (threadIdx.x >> 6);   // 0..32767
    int lane = threadIdx.x & 63;
    int n = wid >> 10, a = wid & 1023;
    const float4* hd = reinterpret_cast<const float4*>(h_dec + (size_t)n * HS);
    const float4* wr = reinterpret_cast<const float4*>(W + (size_t)a * 2048);
    float s = 0.f;
#pragma unroll
    for (int i = 0; i < 4; ++i) {
        float4 h = hd[lane + i * 64];
        float4 w = wr[lane + i * 64];
        s += h.x * w.x + h.y * w.y + h.z * w.z + h.w * w.w;
    }
    for (int off = 32; off; off >>= 1) s += __shfl_xor(s, off);
    if (lane == 0) dproj[wid] = bias[a] + s;
}

// K2: We16[a*1024+e] = (fp16) W[a*2048 + 1024 + e]
__global__ __launch_bounds__(256) void k_cvtW(const float* __restrict__ W,
                                              _Float16* __restrict__ We16) {
    int idx4 = (blockIdx.x * 256 + threadIdx.x) * 4;
    int a = idx4 >> 10;
    int e = idx4 & 1023;
    float4 f = *reinterpret_cast<const float4*>(W + (size_t)a * 2048 + 1024 + e);
    _Float16 h0 = (_Float16)f.x, h1 = (_Float16)f.y, h2 = (_Float16)f.z, h3 = (_Float16)f.w;
    ushort4 p;
    p.x = *(unsigned short*)&h0; p.y = *(unsigned short*)&h1;
    p.z = *(unsigned short*)&h2; p.w = *(unsigned short*)&h3;
    *reinterpret_cast<ushort4*>(We16 + idx4) = p;
}

// K2b: h_enc16 = (fp16) h_enc, streaming.
__global__ __launch_bounds__(256) void k_cvtA(const float* __restrict__ h_enc,
                                              _Float16* __restrict__ h_enc16) {
    size_t idx = ((size_t)blockIdx.x * 256 + threadIdx.x) * 16;
    const float4* g = reinterpret_cast<const float4*>(h_enc + idx);
    _Float16 h[16];
#pragma unroll
    for (int i = 0; i < 4; ++i) {
        float4 f = g[i];
        h[i * 4 + 0] = (_Float16)f.x; h[i * 4 + 1] = (_Float16)f.y;
        h[i * 4 + 2] = (_Float16)f.z; h[i * 4 + 3] = (_Float16)f.w;
    }
    *reinterpret_cast<uint4*>(h_enc16 + idx)     = *reinterpret_cast<uint4*>(&h[0]);
    *reinterpret_cast<uint4*>(h_enc16 + idx + 8) = *reinterpret_cast<uint4*>(&h[8]);
}

// K3: fused score GEMM, counted-vmcnt software pipeline (T3+T4+T2+T5).
// 256t x 256a tile, 512 thr = 8 waves (2m x 4n), wave tile 128t x 64a.
// K = 1024 as 32 tiles of BK=32. LDS ring of 4 one-K-tile buffers
// (A 16KB + B 16KB each, 128KB total): tile kt reads buf kt&3, stages
// tile kt+3 (2 dma/phase). One raw s_barrier per tile preceded by
// s_waitcnt vmcnt(8) (2 tiles in flight) -- never drained to 0 mid-loop.
// Safety: DMA writes into buf b for tile kt+4 are issued only after the
// kt+1 barrier, which all waves reach only after their kt reads of buf b
// completed (compiler lgkm-waits before the dependent MFMAs).
// Swizzle: 16B granule G -> G ^ ((G>>3)&7), self-inverse; applied on the
// global *source* address (linear LDS dest, global_load_lds constraint)
// and on the ds_read offsets. Bank histogram exactly uniform (2-way, free).
__global__ __launch_bounds__(512, 2) void k_score8(
        const _Float16* __restrict__ h_enc16, const _Float16* __restrict__ We16,
        const float* __restrict__ dproj, const float* __restrict__ v,
        float* __restrict__ scores) {
    __shared__ _Float16 As[4][256 * 32];   // 4 x 16 KB
    __shared__ _Float16 Bs[4][256 * 32];   // 4 x 16 KB
    __shared__ float s_acc[256];

    const int tid = threadIdx.x;
    // XCD-bijective swizzle: 1024 wgs, 8 XCDs, 128 consecutive ords per XCD;
    // the 4 a-blocks sharing one A-tile are consecutive ords -> same XCD L2.
    const int ord = ((blockIdx.x & 7) << 7) | (blockIdx.x >> 3);
    const int aT = ord & 3, tT = (ord >> 2) & 7, n = ord >> 5;
    const int t0 = tT << 8, a0 = aT << 8;

    if (tid < 256) s_acc[tid] = 0.0f;

    const int w = tid >> 6, lane = tid & 63;
    const int wm = w >> 2, wn = w & 3;
    const int col = lane & 15, quad = lane >> 4;

    // Staging source map: phys granule Gp = c*512+tid (linear LDS dest);
    // logical Gl = Gp ^ ((Gp>>3)&7); row r = Gl>>2, granule g = Gl&3.
    const _Float16* srcA[2];
    const _Float16* srcB[2];
#pragma unroll
    for (int c = 0; c < 2; ++c) {
        int Gp = c * 512 + tid;
        int Gl = Gp ^ ((Gp >> 3) & 7);
        int r = Gl >> 2, g = Gl & 3;
        srcA[c] = h_enc16 + ((size_t)(n * TT + t0 + r)) * HS + g * 8;
        srcB[c] = We16 + ((size_t)(a0 + r)) * HS + g * 8;
    }

    // Pre-swizzled ds_read byte offsets. Logical: row r, halves quad*8..+7.
    int offA[8], offB[4];
#pragma unroll
    for (int mi = 0; mi < 8; ++mi) {
        int r = wm * 128 + mi * 16 + col;
        offA[mi] = (r * 64 + quad * 16) ^ (((r >> 1) & 7) << 4);
    }
#pragma unroll
    for (int ni = 0; ni < 4; ++ni) {
        int r = wn * 64 + ni * 16 + col;
        offB[ni] = (r * 64 + quad * 16) ^ (((r >> 1) & 7) << 4);
    }

    floatx4 acc[8][4];
#pragma unroll
    for (int mi = 0; mi < 8; ++mi)
#pragma unroll
        for (int ni = 0; ni < 4; ++ni) acc[mi][ni] = (floatx4)0.0f;

    auto issue2 = [&](int kt, int c) {
        const int b = kt & 3;
        dma16(srcA[c] + kt * 32, &As[b][c * 4096 + w * 512]);
        dma16(srcB[c] + kt * 32, &Bs[b][c * 4096 + w * 512]);
    };

    // prologue: stage tiles 0..2 (12 DMA / thread in flight)
#pragma unroll
    for (int kt = 0; kt < 3; ++kt) { issue2(kt, 0); issue2(kt, 1); }

    for (int kt = 0; kt < 32; ++kt) {
        const int b = kt & 3;
        // counted waitcnt: tile kt landed when <= 8 (=tiles kt+1,kt+2) remain
        if (kt < 30)       asm volatile("s_waitcnt vmcnt(8)" ::: "memory");
        else if (kt == 30) asm volatile("s_waitcnt vmcnt(4)" ::: "memory");
        else               asm volatile("s_waitcnt vmcnt(0)" ::: "memory");
        __builtin_amdgcn_s_barrier();
        __builtin_amdgcn_sched_barrier(0);

        const char* Ab = (const char*)As[b];
        const char* Bb = (const char*)Bs[b];
        half8 af[4], bf[4];
        // phase 0: B frags (whole tile) + A frags mi 0..3
#pragma unroll
        for (int ni = 0; ni < 4; ++ni)
            bf[ni] = *reinterpret_cast<const half8*>(Bb + offB[ni]);
#pragma unroll
        for (int mi = 0; mi < 4; ++mi)
            af[mi] = *reinterpret_cast<const half8*>(Ab + offA[mi]);
        if (kt < 29) issue2(kt + 3, 0);
        __builtin_amdgcn_s_setprio(1);
#pragma unroll
        for (int mi = 0; mi < 4; ++mi)
#pragma unroll
            for (int ni = 0; ni < 4; ++ni)
                acc[mi][ni] = __builtin_amdgcn_mfma_f32_16x16x32_f16(
                    af[mi], bf[ni], acc[mi][ni], 0, 0, 0);
        __builtin_amdgcn_s_setprio(0);

        // phase 1: A frags mi 4..7
#pragma unroll
        for (int mi = 0; mi < 4; ++mi)
            af[mi] = *reinterpret_cast<const half8*>(Ab + offA[4 + mi]);
        if (kt < 29) issue2(kt + 3, 1);
        __builtin_amdgcn_s_setprio(1);
#pragma unroll
        for (int mi = 0; mi < 4; ++mi)
#pragma unroll
            for (int ni = 0; ni < 4; ++ni)
                acc[4 + mi][ni] = __builtin_amdgcn_mfma_f32_16x16x32_f16(
                    af[mi], bf[ni], acc[4 + mi][ni], 0, 0, 0);
        __builtin_amdgcn_s_setprio(0);
    }

    // epilogue: s_acc[t] += sum_a v[a]*tanh(C[t][a] + dproj[a]).
    // C/D layout: col = lane&15 (a), row = quad*4+reg (t).
    // vv/dd loaded only now so no stray VMEM perturbs vmcnt counting above.
    float vv[4], dd[4];
#pragma unroll
    for (int ni = 0; ni < 4; ++ni) {
        const int a = a0 + wn * 64 + ni * 16 + col;
        vv[ni] = v[a];
        dd[ni] = dproj[n * HS + a];
    }
#pragma unroll
    for (int mi = 0; mi < 8; ++mi) {
#pragma unroll
        for (int rg = 0; rg < 4; ++rg) {
            float s = 0.0f;
#pragma unroll
            for (int ni = 0; ni < 4; ++ni) {
                float x = acc[mi][ni][rg] + dd[ni];
                float e2 = __expf(2.0f * x);
                float th = 1.0f - 2.0f * __builtin_amdgcn_rcpf(e2 + 1.0f);
                s += vv[ni] * th;
            }
            s += __shfl_xor(s, 8);
            s += __shfl_xor(s, 4);
            s += __shfl_xor(s, 2);
            s += __shfl_xor(s, 1);
            if (col == 0)
                atomicAdd(&s_acc[wm * 128 + mi * 16 + quad * 4 + rg], s);
        }
    }
    __syncthreads();
    // a-dim split over 4 blocks -> global atomic reduction (scores pre-zeroed)
    if (tid < 256)
        atomicAdd(&scores[(size_t)n * TT + t0 + tid], s_acc[tid]);
}

// K4: masked softmax per row, in place.
__global__ __launch_bounds__(256) void k_softmax(float* __restrict__ wout,
                                                 const int* __restrict__ lens) {
    __shared__ float red[4];
    __shared__ float red2[4];
    int n = blockIdx.x, tid = threadIdx.x;
    int len = lens[n];
    float* row = wout + (size_t)n * TT;
    float sv[8];
    float m = -3.0e38f;
#pragma unroll
    for (int i = 0; i < 8; ++i) {
        int t = tid + i * 256;
        float s = row[t];
        s = (t < len) ? s : -1.0e10f;
        sv[i] = s;
        m = fmaxf(m, s);
    }
    for (int off = 1; off <= 32; off <<= 1) m = fmaxf(m, __shfl_xor(m, off));
    if ((tid & 63) == 0) red[tid >> 6] = m;
    __syncthreads();
    m = fmaxf(fmaxf(red[0], red[1]), fmaxf(red[2], red[3]));
    float sum = 0.f, es[8];
#pragma unroll
    for (int i = 0; i < 8; ++i) { es[i] = __expf(sv[i] - m); sum += es[i]; }
    for (int off = 1; off <= 32; off <<= 1) sum += __shfl_xor(sum, off);
    if ((tid & 63) == 0) red2[tid >> 6] = sum;
    __syncthreads();
    sum = red2[0] + red2[1] + red2[2] + red2[3];
    float rinv = 1.0f / sum;
#pragma unroll
    for (int i = 0; i < 8; ++i) row[tid + i * 256] = es[i] * rinv;
}

// K5: ctx[n,e] = sum_t w[n,t] * h_enc16[n,t,e]; t-split via atomics.
__global__ __launch_bounds__(256) void k_ctx(const _Float16* __restrict__ h_enc16,
                                             const float* __restrict__ wts,
                                             float* __restrict__ ctx) {
    __shared__ float red[256][8];
    int b = blockIdx.x;               // 512 blocks: n(32) x ec(4) x ts(4)
    int n  = b >> 4;
    int ec = (b >> 2) & 3;
    int ts = b & 3;
    int tid = threadIdx.x;
    int q = tid & 31, tg = tid >> 5;
    int e = ec * 256 + q * 8;
    float acc[8];
#pragma unroll
    for (int j = 0; j < 8; ++j) acc[j] = 0.f;
    const float* wrow = wts + (size_t)n * TT;
    for (int t = ts * 512 + tg; t < ts * 512 + 512; t += 8) {
        float w = wrow[t];
        uint4 raw = *reinterpret_cast<const uint4*>(
            h_enc16 + ((size_t)(n * TT + t)) * HS + e);
        const _Float16* hp = reinterpret_cast<const _Float16*>(&raw);
#pragma unroll
        for (int j = 0; j < 8; ++j) acc[j] += w * (float)hp[j];
    }
#pragma unroll
    for (int j = 0; j < 8; ++j) red[tid][j] = acc[j];
    __syncthreads();
    if (tid < 32) {
        float s[8];
#pragma unroll
        for (int j = 0; j < 8; ++j) s[j] = red[tid][j];
        for (int g = 1; g < 8; ++g)
#pragma unroll
            for (int j = 0; j < 8; ++j) s[j] += red[g * 32 + tid][j];
        float* dst = ctx + (size_t)n * HS + ec * 256 + tid * 8;
#pragma unroll
        for (int j = 0; j < 8; ++j) atomicAdd(dst + j, s[j]);
    }
}

// ---------- slow-but-correct fallback (only if ws is too small; unexpected) ----------
__global__ __launch_bounds__(256) void k_score_naive(const float* __restrict__ h_enc,
                                                     const float* __restrict__ W,
                                                     const float* __restrict__ dproj,
                                                     const float* __restrict__ v,
                                                     float* __restrict__ scores) {
    int gw = blockIdx.x * 4 + (threadIdx.x >> 6);   // wave per (n,t)
    int lane = threadIdx.x & 63;
    int n = gw >> 11, t = gw & 2047;
    const float4* he = reinterpret_cast<const float4*>(h_enc + ((size_t)(n * TT + t)) * HS);
    float4 hv[4];
#pragma unroll
    for (int i = 0; i < 4; ++i) hv[i] = he[lane + i * 64];
    float s = 0.f;
    for (int a = 0; a < 1024; ++a) {
        const float4* wr = reinterpret_cast<const float4*>(W + (size_t)a * 2048 + 1024);
        float d = 0.f;
#pragma unroll
        for (int i = 0; i < 4; ++i) {
            float4 wv = wr[lane + i * 64];
            d += hv[i].x * wv.x + hv[i].y * wv.y + hv[i].z * wv.z + hv[i].w * wv.w;
        }
        for (int off = 32; off; off >>= 1) d += __shfl_xor(d, off);
        s += v[a] * tanhf(d + dproj[n * HS + a]);
    }
    if (lane == 0) scores[(size_t)n * TT + t] = s;
}

__global__ __launch_bounds__(256) void k_ctx_naive(const float* __restrict__ h_enc,
                                                   const float* __restrict__ wts,
                                                   float* __restrict__ ctx) {
    int n = blockIdx.x;
    int e = threadIdx.x * 4;
    float4 a = make_float4(0.f, 0.f, 0.f, 0.f);
    const float* wrow = wts + (size_t)n * TT;
    for (int t = 0; t < TT; ++t) {
        float w = wrow[t];
        float4 h = *reinterpret_cast<const float4*>(h_enc + ((size_t)(n * TT + t)) * HS + e);
        a.x += w * h.x; a.y += w * h.y; a.z += w * h.z; a.w += w * h.w;
    }
    *reinterpret_cast<float4*>(ctx + (size_t)n * HS + e) = a;
}

extern "C" void kernel_launch(void* const* d_in, const int* in_sizes, int n_in,
                              void* d_out, int out_size, void* d_ws, size_t ws_size,
                              hipStream_t stream) {
    const float* h_dec    = (const float*)d_in[0];
    const float* h_enc    = (const float*)d_in[1];
    const int*   src_lens = (const int*)d_in[2];
    const float* W = (const float*)d_in[3];
    const float* b = (const float*)d_in[4];
    const float* v = (const float*)d_in[5];

    float* out = (float*)d_out;
    float* ctx = out;                 // 32*1024
    float* wts = out + 32 * 1024;     // 32*2048 (scores, then weights in place)

    float*    dproj   = (float*)d_ws;                                  // 128 KB
    _Float16* We16    = (_Float16*)((char*)d_ws + 131072);             // 2 MB
    _Float16* h_enc16 = (_Float16*)((char*)d_ws + 131072 + 2097152);   // 128 MB
    const size_t need = 131072 + 2097152 + (size_t)32 * TT * HS * 2;

    k_dproj<<<8192, 256, 0, stream>>>(h_dec, W, b, dproj);
    if (ws_size >= need) {
        (void)hipMemsetAsync(ctx, 0, 32 * 1024 * sizeof(float), stream);
        (void)hipMemsetAsync(wts, 0, (size_t)32 * TT * sizeof(float), stream);
        k_cvtW <<<1024, 256, 0, stream>>>(W, We16);
        k_cvtA <<<16384, 256, 0, stream>>>(h_enc, h_enc16);
        k_score8<<<1024, 512, 0, stream>>>(h_enc16, We16, dproj, v, wts);
        k_softmax<<<32, 256, 0, stream>>>(wts, src_lens);
        k_ctx  <<<512, 256, 0, stream>>>(h_enc16, wts, ctx);
    } else {
        k_score_naive<<<16384, 256, 0, stream>>>(h_enc, W, dproj, v, wts);
        k_softmax<<<32, 256, 0, stream>>>(wts, src_lens);
        k_ctx_naive<<<32, 256, 0, stream>>>(h_enc, wts, ctx);
    }
}

// Round 2
// 598.275 us; speedup vs baseline: 1.0024x; 1.0024x over previous
//
#include <hip/hip_runtime.h>
#include <hip/hip_fp16.h>

#define HS 1024
#define TT 2048

typedef _Float16 half8 __attribute__((ext_vector_type(8)));
typedef float floatx4 __attribute__((ext_vector_type(4)));

// Async global->LDS DMA, 16B per lane. LDS dest = wave-uniform base + lane*16.
__device__ __forceinline__ void dma16(const _Float16* g, _Float16* l) {
    __builtin_amdgcn_global_load_lds(
        (const __attribute__((address_space(1))) unsigned int*)g,
        (__attribute__((address_space(3))) unsigned int*)l, 16, 0, 0);
}

// K1: dproj[n*1024+a] = bias[a] + sum_e h_dec[n,e]*W[a,e]. One wave per (n,a).
__global__ __launch_bounds__(256) void k_dproj(const float* __restrict__ h_dec,
                                               const float* __restrict__ W,
                                               const float* __restrict__ bias,
                                               float* __restrict__ dproj) {
    int wid = blockIdx.x * 4 + (threadIdx.x >> 6);   // 0..32767
    int lane = threadIdx.x & 63;
    int n = wid >> 10, a = wid & 1023;
    const float4* hd = reinterpret_cast<const float4*>(h_dec + (size_t)n * HS);
    const float4* wr = reinterpret_cast<const float4*>(W + (size_t)a * 2048);
    float s = 0.f;
#pragma unroll
    for (int i = 0; i < 4; ++i) {
        float4 h = hd[lane + i * 64];
        float4 w = wr[lane + i * 64];
        s += h.x * w.x + h.y * w.y + h.z * w.z + h.w * w.w;
    }
    for (int off = 32; off; off >>= 1) s += __shfl_xor(s, off);
    if (lane == 0) dproj[wid] = bias[a] + s;
}

// K2: We16[a*1024+e] = (fp16) W[a*2048 + 1024 + e]
__global__ __launch_bounds__(256) void k_cvtW(const float* __restrict__ W,
                                              _Float16* __restrict__ We16) {
    int idx4 = (blockIdx.x * 256 + threadIdx.x) * 4;
    int a = idx4 >> 10;
    int e = idx4 & 1023;
    float4 f = *reinterpret_cast<const float4*>(W + (size_t)a * 2048 + 1024 + e);
    _Float16 h0 = (_Float16)f.x, h1 = (_Float16)f.y, h2 = (_Float16)f.z, h3 = (_Float16)f.w;
    ushort4 p;
    p.x = *(unsigned short*)&h0; p.y = *(unsigned short*)&h1;
    p.z = *(unsigned short*)&h2; p.w = *(unsigned short*)&h3;
    *reinterpret_cast<ushort4*>(We16 + idx4) = p;
}

// K2b: h_enc16 = (fp16) h_enc, streaming.
__global__ __launch_bounds__(256) void k_cvtA(const float* __restrict__ h_enc,
                                              _Float16* __restrict__ h_enc16) {
    size_t idx = ((size_t)blockIdx.x * 256 + threadIdx.x) * 16;
    const float4* g = reinterpret_cast<const float4*>(h_enc + idx);
    _Float16 h[16];
#pragma unroll
    for (int i = 0; i < 4; ++i) {
        float4 f = g[i];
        h[i * 4 + 0] = (_Float16)f.x; h[i * 4 + 1] = (_Float16)f.y;
        h[i * 4 + 2] = (_Float16)f.z; h[i * 4 + 3] = (_Float16)f.w;
    }
    *reinterpret_cast<uint4*>(h_enc16 + idx)     = *reinterpret_cast<uint4*>(&h[0]);
    *reinterpret_cast<uint4*>(h_enc16 + idx + 8) = *reinterpret_cast<uint4*>(&h[8]);
}

// K3: fused score GEMM — 8-phase-style fine interleave (T2+T3+T4+T5).
// 256t x 256a tile, 512 thr = 8 waves (2m x 4n), wave tile 128t x 64a.
// K = 1024 as 32 tiles of BK=32, LDS ring of 4 (A 16KB + B 16KB per tile,
// 128 KB -> 1 block/CU, 2 waves/SIMD).
// Per K-tile j: 2 phases, each = { ds_read frags for THIS phase's MFMAs,
// issue 2 global_load_lds (A resp. B of tile j+3), s_barrier,
// s_waitcnt lgkmcnt(0)+sched_barrier(0) [rule 18], setprio(1), 16 MFMA,
// setprio(0), s_barrier } -- reads issued pre-barrier, consumed post-barrier;
// 8 MFMA per barrier (iso-density with the verified m201 template).
// Counted vmcnt(8) once per K-tile at phase 1 (tile j+1 guaranteed landed
// before its first reads; tiles j+2, j+3 = 8 loads left in flight); never 0
// in steady state; tail drains 8 -> 4 -> 0.
// Safety: reads of buf j&3 sit between the vmcnt-covered barrier of phase
// (j-1,1) and phase (j,1)'s close; DMA writes into buf (j+3)&3 = (j-1)&3
// are issued at phase (j,0), after the block-wide barrier that closed all
// reads of tile j-1. FIFO issue order (A then B, tile-ordered) keeps the
// per-wave vmcnt counting exact (4 loads/wave/tile).
// Swizzle (proven 0-conflict in r1): 16B granule G -> G ^ ((G>>3)&7),
// self-inverse; applied on the pre-swizzled global source (linear LDS dest)
// and on the ds_read offsets.
__global__ __launch_bounds__(512, 2) void k_score8(
        const _Float16* __restrict__ h_enc16, const _Float16* __restrict__ We16,
        const float* __restrict__ dproj, const float* __restrict__ v,
        float* __restrict__ scores) {
    __shared__ _Float16 As[4][256 * 32];   // 4 x 16 KB
    __shared__ _Float16 Bs[4][256 * 32];   // 4 x 16 KB
    __shared__ float s_acc[256];

    const int tid = threadIdx.x;
    // XCD-bijective swizzle: 1024 wgs, 8 XCDs, 128 consecutive ords per XCD;
    // the 4 a-blocks sharing one A-tile are consecutive ords -> same XCD L2.
    const int ord = ((blockIdx.x & 7) << 7) | (blockIdx.x >> 3);
    const int aT = ord & 3, tT = (ord >> 2) & 7, n = ord >> 5;
    const int t0 = tT << 8, a0 = aT << 8;

    if (tid < 256) s_acc[tid] = 0.0f;

    const int w = tid >> 6, lane = tid & 63;
    const int wm = w >> 2, wn = w & 3;
    const int col = lane & 15, quad = lane >> 4;

    // Staging source map: phys granule Gp = c*512+tid (linear LDS dest);
    // logical Gl = Gp ^ ((Gp>>3)&7); row r = Gl>>2, granule g = Gl&3.
    const _Float16* srcA[2];
    const _Float16* srcB[2];
#pragma unroll
    for (int c = 0; c < 2; ++c) {
        int Gp = c * 512 + tid;
        int Gl = Gp ^ ((Gp >> 3) & 7);
        int r = Gl >> 2, g = Gl & 3;
        srcA[c] = h_enc16 + ((size_t)(n * TT + t0 + r)) * HS + g * 8;
        srcB[c] = We16 + ((size_t)(a0 + r)) * HS + g * 8;
    }

    // Pre-swizzled ds_read byte offsets. Logical: row r, halves quad*8..+7.
    int offA[8], offB[4];
#pragma unroll
    for (int mi = 0; mi < 8; ++mi) {
        int r = wm * 128 + mi * 16 + col;
        offA[mi] = (r * 64 + quad * 16) ^ (((r >> 1) & 7) << 4);
    }
#pragma unroll
    for (int ni = 0; ni < 4; ++ni) {
        int r = wn * 64 + ni * 16 + col;
        offB[ni] = (r * 64 + quad * 16) ^ (((r >> 1) & 7) << 4);
    }

    floatx4 acc[8][4];
#pragma unroll
    for (int mi = 0; mi < 8; ++mi)
#pragma unroll
        for (int ni = 0; ni < 4; ++ni) acc[mi][ni] = (floatx4)0.0f;

    auto issueA = [&](int kt) {
        const int b = kt & 3;
#pragma unroll
        for (int c = 0; c < 2; ++c)
            dma16(srcA[c] + kt * 32, &As[b][c * 4096 + w * 512]);
    };
    auto issueB = [&](int kt) {
        const int b = kt & 3;
#pragma unroll
        for (int c = 0; c < 2; ++c)
            dma16(srcB[c] + kt * 32, &Bs[b][c * 4096 + w * 512]);
    };

    // prologue: stage tiles 0,1,2 in FIFO order (12 loads/wave in flight)
#pragma unroll
    for (int kt = 0; kt < 3; ++kt) { issueA(kt); issueB(kt); }
    asm volatile("s_waitcnt vmcnt(8)" ::: "memory");   // tile 0 landed
    __builtin_amdgcn_s_barrier();

    for (int j = 0; j < 32; ++j) {
        const int b = j & 3;
        const char* Ab = (const char*)As[b];
        const char* Bb = (const char*)Bs[b];
        half8 af[4], bf[4];

        // ---------------- phase 0: mi 0..3 ----------------
#pragma unroll
        for (int ni = 0; ni < 4; ++ni)
            bf[ni] = *reinterpret_cast<const half8*>(Bb + offB[ni]);
#pragma unroll
        for (int mi = 0; mi < 4; ++mi)
            af[mi] = *reinterpret_cast<const half8*>(Ab + offA[mi]);
        if (j < 29) issueA(j + 3);
        __builtin_amdgcn_sched_barrier(0);
        __builtin_amdgcn_s_barrier();
        asm volatile("s_waitcnt lgkmcnt(0)" ::: "memory");
        __builtin_amdgcn_sched_barrier(0);
        __builtin_amdgcn_s_setprio(1);
#pragma unroll
        for (int mi = 0; mi < 4; ++mi)
#pragma unroll
            for (int ni = 0; ni < 4; ++ni)
                acc[mi][ni] = __builtin_amdgcn_mfma_f32_16x16x32_f16(
                    af[mi], bf[ni], acc[mi][ni], 0, 0, 0);
        __builtin_amdgcn_s_setprio(0);
        __builtin_amdgcn_sched_barrier(0);
        __builtin_amdgcn_s_barrier();

        // ---------------- phase 1: mi 4..7 ----------------
#pragma unroll
        for (int mi = 0; mi < 4; ++mi)
            af[mi] = *reinterpret_cast<const half8*>(Ab + offA[4 + mi]);
        if (j < 29) issueB(j + 3);
        __builtin_amdgcn_sched_barrier(0);
        __builtin_amdgcn_s_barrier();
        asm volatile("s_waitcnt lgkmcnt(0)" ::: "memory");
        __builtin_amdgcn_sched_barrier(0);
        __builtin_amdgcn_s_setprio(1);
#pragma unroll
        for (int mi = 0; mi < 4; ++mi)
#pragma unroll
            for (int ni = 0; ni < 4; ++ni)
                acc[4 + mi][ni] = __builtin_amdgcn_mfma_f32_16x16x32_f16(
                    af[mi], bf[ni], acc[4 + mi][ni], 0, 0, 0);
        __builtin_amdgcn_s_setprio(0);
        // counted vmcnt, once per K-tile: tile j+1 landed before its reads;
        // tiles j+2 and j+3 (8 loads) stay in flight. Tail: 8 -> 4 -> 0.
        if (j < 29)       asm volatile("s_waitcnt vmcnt(8)" ::: "memory");
        else if (j == 29) asm volatile("s_waitcnt vmcnt(4)" ::: "memory");
        else if (j == 30) asm volatile("s_waitcnt vmcnt(0)" ::: "memory");
        __builtin_amdgcn_sched_barrier(0);
        __builtin_amdgcn_s_barrier();
    }

    // epilogue: s_acc[t] += sum_a v[a]*tanh(C[t][a] + dproj[a]).
    // C/D layout: col = lane&15 (a), row = quad*4+reg (t).
    // vv/dd loaded only now so no stray VMEM perturbs vmcnt counting above.
    float vv[4], dd[4];
#pragma unroll
    for (int ni = 0; ni < 4; ++ni) {
        const int a = a0 + wn * 64 + ni * 16 + col;
        vv[ni] = v[a];
        dd[ni] = dproj[n * HS + a];
    }
#pragma unroll
    for (int mi = 0; mi < 8; ++mi) {
#pragma unroll
        for (int rg = 0; rg < 4; ++rg) {
            float s = 0.0f;
#pragma unroll
            for (int ni = 0; ni < 4; ++ni) {
                float x = acc[mi][ni][rg] + dd[ni];
                float e2 = __expf(2.0f * x);
                float th = 1.0f - 2.0f * __builtin_amdgcn_rcpf(e2 + 1.0f);
                s += vv[ni] * th;
            }
            s += __shfl_xor(s, 8);
            s += __shfl_xor(s, 4);
            s += __shfl_xor(s, 2);
            s += __shfl_xor(s, 1);
            if (col == 0)
                atomicAdd(&s_acc[wm * 128 + mi * 16 + quad * 4 + rg], s);
        }
    }
    __syncthreads();
    // a-dim split over 4 blocks -> global atomic reduction (scores pre-zeroed)
    if (tid < 256)
        atomicAdd(&scores[(size_t)n * TT + t0 + tid], s_acc[tid]);
}

// K4: masked softmax per row, in place.
__global__ __launch_bounds__(256) void k_softmax(float* __restrict__ wout,
                                                 const int* __restrict__ lens) {
    __shared__ float red[4];
    __shared__ float red2[4];
    int n = blockIdx.x, tid = threadIdx.x;
    int len = lens[n];
    float* row = wout + (size_t)n * TT;
    float sv[8];
    float m = -3.0e38f;
#pragma unroll
    for (int i = 0; i < 8; ++i) {
        int t = tid + i * 256;
        float s = row[t];
        s = (t < len) ? s : -1.0e10f;
        sv[i] = s;
        m = fmaxf(m, s);
    }
    for (int off = 1; off <= 32; off <<= 1) m = fmaxf(m, __shfl_xor(m, off));
    if ((tid & 63) == 0) red[tid >> 6] = m;
    __syncthreads();
    m = fmaxf(fmaxf(red[0], red[1]), fmaxf(red[2], red[3]));
    float sum = 0.f, es[8];
#pragma unroll
    for (int i = 0; i < 8; ++i) { es[i] = __expf(sv[i] - m); sum += es[i]; }
    for (int off = 1; off <= 32; off <<= 1) sum += __shfl_xor(sum, off);
    if ((tid & 63) == 0) red2[tid >> 6] = sum;
    __syncthreads();
    sum = red2[0] + red2[1] + red2[2] + red2[3];
    float rinv = 1.0f / sum;
#pragma unroll
    for (int i = 0; i < 8; ++i) row[tid + i * 256] = es[i] * rinv;
}

// K5: ctx[n,e] = sum_t w[n,t] * h_enc16[n,t,e]; t-split via atomics.
__global__ __launch_bounds__(256) void k_ctx(const _Float16* __restrict__ h_enc16,
                                             const float* __restrict__ wts,
                                             float* __restrict__ ctx) {
    __shared__ float red[256][8];
    int b = blockIdx.x;               // 512 blocks: n(32) x ec(4) x ts(4)
    int n  = b >> 4;
    int ec = (b >> 2) & 3;
    int ts = b & 3;
    int tid = threadIdx.x;
    int q = tid & 31, tg = tid >> 5;
    int e = ec * 256 + q * 8;
    float acc[8];
#pragma unroll
    for (int j = 0; j < 8; ++j) acc[j] = 0.f;
    const float* wrow = wts + (size_t)n * TT;
    for (int t = ts * 512 + tg; t < ts * 512 + 512; t += 8) {
        float w = wrow[t];
        uint4 raw = *reinterpret_cast<const uint4*>(
            h_enc16 + ((size_t)(n * TT + t)) * HS + e);
        const _Float16* hp = reinterpret_cast<const _Float16*>(&raw);
#pragma unroll
        for (int j = 0; j < 8; ++j) acc[j] += w * (float)hp[j];
    }
#pragma unroll
    for (int j = 0; j < 8; ++j) red[tid][j] = acc[j];
    __syncthreads();
    if (tid < 32) {
        float s[8];
#pragma unroll
        for (int j = 0; j < 8; ++j) s[j] = red[tid][j];
        for (int g = 1; g < 8; ++g)
#pragma unroll
            for (int j = 0; j < 8; ++j) s[j] += red[g * 32 + tid][j];
        float* dst = ctx + (size_t)n * HS + ec * 256 + tid * 8;
#pragma unroll
        for (int j = 0; j < 8; ++j) atomicAdd(dst + j, s[j]);
    }
}

// ---------- slow-but-correct fallback (only if ws is too small; unexpected) ----------
__global__ __launch_bounds__(256) void k_score_naive(const float* __restrict__ h_enc,
                                                     const float* __restrict__ W,
                                                     const float* __restrict__ dproj,
                                                     const float* __restrict__ v,
                                                     float* __restrict__ scores) {
    int gw = blockIdx.x * 4 + (threadIdx.x >> 6);   // wave per (n,t)
    int lane = threadIdx.x & 63;
    int n = gw >> 11, t = gw & 2047;
    const float4* he = reinterpret_cast<const float4*>(h_enc + ((size_t)(n * TT + t)) * HS);
    float4 hv[4];
#pragma unroll
    for (int i = 0; i < 4; ++i) hv[i] = he[lane + i * 64];
    float s = 0.f;
    for (int a = 0; a < 1024; ++a) {
        const float4* wr = reinterpret_cast<const float4*>(W + (size_t)a * 2048 + 1024);
        float d = 0.f;
#pragma unroll
        for (int i = 0; i < 4; ++i) {
            float4 wv = wr[lane + i * 64];
            d += hv[i].x * wv.x + hv[i].y * wv.y + hv[i].z * wv.z + hv[i].w * wv.w;
        }
        for (int off = 32; off; off >>= 1) d += __shfl_xor(d, off);
        s += v[a] * tanhf(d + dproj[n * HS + a]);
    }
    if (lane == 0) scores[(size_t)n * TT + t] = s;
}

__global__ __launch_bounds__(256) void k_ctx_naive(const float* __restrict__ h_enc,
                                                   const float* __restrict__ wts,
                                                   float* __restrict__ ctx) {
    int n = blockIdx.x;
    int e = threadIdx.x * 4;
    float4 a = make_float4(0.f, 0.f, 0.f, 0.f);
    const float* wrow = wts + (size_t)n * TT;
    for (int t = 0; t < TT; ++t) {
        float w = wrow[t];
        float4 h = *reinterpret_cast<const float4*>(h_enc + ((size_t)(n * TT + t)) * HS + e);
        a.x += w * h.x; a.y += w * h.y; a.z += w * h.z; a.w += w * h.w;
    }
    *reinterpret_cast<float4*>(ctx + (size_t)n * HS + e) = a;
}

extern "C" void kernel_launch(void* const* d_in, const int* in_sizes, int n_in,
                              void* d_out, int out_size, void* d_ws, size_t ws_size,
                              hipStream_t stream) {
    const float* h_dec    = (const float*)d_in[0];
    const float* h_enc    = (const float*)d_in[1];
    const int*   src_lens = (const int*)d_in[2];
    const float* W = (const float*)d_in[3];
    const float* b = (const float*)d_in[4];
    const float* v = (const float*)d_in[5];

    float* out = (float*)d_out;
    float* ctx = out;                 // 32*1024
    float* wts = out + 32 * 1024;     // 32*2048 (scores, then weights in place)

    float*    dproj   = (float*)d_ws;                                  // 128 KB
    _Float16* We16    = (_Float16*)((char*)d_ws + 131072);             // 2 MB
    _Float16* h_enc16 = (_Float16*)((char*)d_ws + 131072 + 2097152);   // 128 MB
    const size_t need = 131072 + 2097152 + (size_t)32 * TT * HS * 2;

    k_dproj<<<8192, 256, 0, stream>>>(h_dec, W, b, dproj);
    if (ws_size >= need) {
        (void)hipMemsetAsync(ctx, 0, 32 * 1024 * sizeof(float), stream);
        (void)hipMemsetAsync(wts, 0, (size_t)32 * TT * sizeof(float), stream);
        k_cvtW <<<1024, 256, 0, stream>>>(W, We16);
        k_cvtA <<<16384, 256, 0, stream>>>(h_enc, h_enc16);
        k_score8<<<1024, 512, 0, stream>>>(h_enc16, We16, dproj, v, wts);
        k_softmax<<<32, 256, 0, stream>>>(wts, src_lens);
        k_ctx  <<<512, 256, 0, stream>>>(h_enc16, wts, ctx);
    } else {
        k_score_naive<<<16384, 256, 0, stream>>>(h_enc, W, dproj, v, wts);
        k_softmax<<<32, 256, 0, stream>>>(wts, src_lens);
        k_ctx_naive<<<32, 256, 0, stream>>>(h_enc, wts, ctx);
    }
}

// Round 3
// 492.453 us; speedup vs baseline: 1.2179x; 1.2149x over previous
//
#include <hip/hip_runtime.h>
#include <hip/hip_fp16.h>

#define HS 1024
#define TT 2048

typedef _Float16 half8 __attribute__((ext_vector_type(8)));
typedef float floatx4 __attribute__((ext_vector_type(4)));

// Async global->LDS DMA, 16B per lane. LDS dest = wave-uniform base + lane*16.
__device__ __forceinline__ void dma16(const _Float16* g, _Float16* l) {
    __builtin_amdgcn_global_load_lds(
        (const __attribute__((address_space(1))) unsigned int*)g,
        (__attribute__((address_space(3))) unsigned int*)l, 16, 0, 0);
}

// ---------------- fused pre-pass: cvtA(+len skip) | dproj | cvtW | zeroing ----
// block ranges: [0,16384) cvtA, [16384,24576) dproj, [24576,25600) cvtW,
// [25600,25664) zero scores(ws), [25664,25696) zero ctx(out).
__global__ __launch_bounds__(256) void k_pre(const float* __restrict__ h_enc,
                                             _Float16* __restrict__ h_enc16,
                                             const float* __restrict__ h_dec,
                                             const float* __restrict__ W,
                                             const float* __restrict__ bias,
                                             const int* __restrict__ lens,
                                             float* __restrict__ dproj,
                                             _Float16* __restrict__ We16,
                                             float* __restrict__ sc,
                                             float* __restrict__ ctx) {
    const int b = blockIdx.x;
    const int tid = threadIdx.x;
    if (b < 16384) {
        // cvtA: block covers 4 t-rows of one n. Rows t >= roundup256(len) are
        // never read (k_score skips those tiles; k_ctxsm clamps to len).
        const int n = b >> 9;
        const int t4 = (b & 511) * 4;
        const int lim = (lens[n] + 255) & ~255;
        if (t4 >= lim) return;
        size_t idx = ((size_t)b * 256 + tid) * 16;
        const float4* g = reinterpret_cast<const float4*>(h_enc + idx);
        _Float16 h[16];
#pragma unroll
        for (int i = 0; i < 4; ++i) {
            float4 f = g[i];
            h[i * 4 + 0] = (_Float16)f.x; h[i * 4 + 1] = (_Float16)f.y;
            h[i * 4 + 2] = (_Float16)f.z; h[i * 4 + 3] = (_Float16)f.w;
        }
        *reinterpret_cast<uint4*>(h_enc16 + idx)     = *reinterpret_cast<uint4*>(&h[0]);
        *reinterpret_cast<uint4*>(h_enc16 + idx + 8) = *reinterpret_cast<uint4*>(&h[8]);
    } else if (b < 24576) {
        // dproj: one wave per (n,a)
        int wid = (b - 16384) * 4 + (tid >> 6);
        int lane = tid & 63;
        int n = wid >> 10, a = wid & 1023;
        const float4* hd = reinterpret_cast<const float4*>(h_dec + (size_t)n * HS);
        const float4* wr = reinterpret_cast<const float4*>(W + (size_t)a * 2048);
        float s = 0.f;
#pragma unroll
        for (int i = 0; i < 4; ++i) {
            float4 h = hd[lane + i * 64];
            float4 w = wr[lane + i * 64];
            s += h.x * w.x + h.y * w.y + h.z * w.z + h.w * w.w;
        }
        for (int off = 32; off; off >>= 1) s += __shfl_xor(s, off);
        if (lane == 0) dproj[wid] = bias[a] + s;
    } else if (b < 25600) {
        // cvtW: We16[a*1024+e] = (fp16) W[a*2048 + 1024 + e]
        int idx4 = ((b - 24576) * 256 + tid) * 4;
        int a = idx4 >> 10;
        int e = idx4 & 1023;
        float4 f = *reinterpret_cast<const float4*>(W + (size_t)a * 2048 + 1024 + e);
        _Float16 h0 = (_Float16)f.x, h1 = (_Float16)f.y, h2 = (_Float16)f.z, h3 = (_Float16)f.w;
        ushort4 p;
        p.x = *(unsigned short*)&h0; p.y = *(unsigned short*)&h1;
        p.z = *(unsigned short*)&h2; p.w = *(unsigned short*)&h3;
        *reinterpret_cast<ushort4*>(We16 + idx4) = p;
    } else if (b < 25664) {
        reinterpret_cast<float4*>(sc)[(b - 25600) * 256 + tid] =
            make_float4(0.f, 0.f, 0.f, 0.f);
    } else {
        reinterpret_cast<float4*>(ctx)[(b - 25664) * 256 + tid] =
            make_float4(0.f, 0.f, 0.f, 0.f);
    }
}

// K3: fused score GEMM (r1 structure: counted-vmcnt ring-4 pipeline) + masked
// t-tile skip. 256t x 256a tile, 512 thr = 8 waves (2m x 4n), wave 128t x 64a.
// Blocks whose whole t-range is masked (t0 >= len[n]) return immediately:
// scores stay pre-zeroed and are masked downstream (correct for any input).
__global__ __launch_bounds__(512, 2) void k_score8(
        const _Float16* __restrict__ h_enc16, const _Float16* __restrict__ We16,
        const float* __restrict__ dproj, const float* __restrict__ v,
        const int* __restrict__ lens, float* __restrict__ scores) {
    __shared__ _Float16 As[4][256 * 32];   // 4 x 16 KB
    __shared__ _Float16 Bs[4][256 * 32];   // 4 x 16 KB
    __shared__ float s_acc[256];

    const int tid = threadIdx.x;
    // XCD-bijective swizzle: 1024 wgs, 8 XCDs, 128 consecutive ords per XCD.
    const int ord = ((blockIdx.x & 7) << 7) | (blockIdx.x >> 3);
    const int aT = ord & 3, tT = (ord >> 2) & 7, n = ord >> 5;
    const int t0 = tT << 8, a0 = aT << 8;

    if (t0 >= lens[n]) return;   // fully-masked tile: skip (block-uniform)

    if (tid < 256) s_acc[tid] = 0.0f;

    const int w = tid >> 6, lane = tid & 63;
    const int wm = w >> 2, wn = w & 3;
    const int col = lane & 15, quad = lane >> 4;

    // Staging source map: phys granule Gp = c*512+tid (linear LDS dest);
    // logical Gl = Gp ^ ((Gp>>3)&7); row r = Gl>>2, granule g = Gl&3.
    const _Float16* srcA[2];
    const _Float16* srcB[2];
#pragma unroll
    for (int c = 0; c < 2; ++c) {
        int Gp = c * 512 + tid;
        int Gl = Gp ^ ((Gp >> 3) & 7);
        int r = Gl >> 2, g = Gl & 3;
        srcA[c] = h_enc16 + ((size_t)(n * TT + t0 + r)) * HS + g * 8;
        srcB[c] = We16 + ((size_t)(a0 + r)) * HS + g * 8;
    }

    // Pre-swizzled ds_read byte offsets (0-conflict, verified r1).
    int offA[8], offB[4];
#pragma unroll
    for (int mi = 0; mi < 8; ++mi) {
        int r = wm * 128 + mi * 16 + col;
        offA[mi] = (r * 64 + quad * 16) ^ (((r >> 1) & 7) << 4);
    }
#pragma unroll
    for (int ni = 0; ni < 4; ++ni) {
        int r = wn * 64 + ni * 16 + col;
        offB[ni] = (r * 64 + quad * 16) ^ (((r >> 1) & 7) << 4);
    }

    floatx4 acc[8][4];
#pragma unroll
    for (int mi = 0; mi < 8; ++mi)
#pragma unroll
        for (int ni = 0; ni < 4; ++ni) acc[mi][ni] = (floatx4)0.0f;

    auto issue2 = [&](int kt, int c) {
        const int b = kt & 3;
        dma16(srcA[c] + kt * 32, &As[b][c * 4096 + w * 512]);
        dma16(srcB[c] + kt * 32, &Bs[b][c * 4096 + w * 512]);
    };

    // prologue: stage tiles 0..2 (12 loads/wave in flight)
#pragma unroll
    for (int kt = 0; kt < 3; ++kt) { issue2(kt, 0); issue2(kt, 1); }

    for (int kt = 0; kt < 32; ++kt) {
        const int b = kt & 3;
        // counted waitcnt: tile kt landed when <= 8 (tiles kt+1,kt+2) remain
        if (kt < 30)       asm volatile("s_waitcnt vmcnt(8)" ::: "memory");
        else if (kt == 30) asm volatile("s_waitcnt vmcnt(4)" ::: "memory");
        else               asm volatile("s_waitcnt vmcnt(0)" ::: "memory");
        __builtin_amdgcn_s_barrier();
        __builtin_amdgcn_sched_barrier(0);

        const char* Ab = (const char*)As[b];
        const char* Bb = (const char*)Bs[b];
        half8 af[4], bf[4];
        // phase 0: B frags + A frags mi 0..3
#pragma unroll
        for (int ni = 0; ni < 4; ++ni)
            bf[ni] = *reinterpret_cast<const half8*>(Bb + offB[ni]);
#pragma unroll
        for (int mi = 0; mi < 4; ++mi)
            af[mi] = *reinterpret_cast<const half8*>(Ab + offA[mi]);
        if (kt < 29) issue2(kt + 3, 0);
        __builtin_amdgcn_s_setprio(1);
#pragma unroll
        for (int mi = 0; mi < 4; ++mi)
#pragma unroll
            for (int ni = 0; ni < 4; ++ni)
                acc[mi][ni] = __builtin_amdgcn_mfma_f32_16x16x32_f16(
                    af[mi], bf[ni], acc[mi][ni], 0, 0, 0);
        __builtin_amdgcn_s_setprio(0);

        // phase 1: A frags mi 4..7
#pragma unroll
        for (int mi = 0; mi < 4; ++mi)
            af[mi] = *reinterpret_cast<const half8*>(Ab + offA[4 + mi]);
        if (kt < 29) issue2(kt + 3, 1);
        __builtin_amdgcn_s_setprio(1);
#pragma unroll
        for (int mi = 0; mi < 4; ++mi)
#pragma unroll
            for (int ni = 0; ni < 4; ++ni)
                acc[4 + mi][ni] = __builtin_amdgcn_mfma_f32_16x16x32_f16(
                    af[mi], bf[ni], acc[4 + mi][ni], 0, 0, 0);
        __builtin_amdgcn_s_setprio(0);
    }

    // epilogue: s_acc[t] += sum_a v[a]*tanh(C[t][a] + dproj[a]).
    float vv[4], dd[4];
#pragma unroll
    for (int ni = 0; ni < 4; ++ni) {
        const int a = a0 + wn * 64 + ni * 16 + col;
        vv[ni] = v[a];
        dd[ni] = dproj[n * HS + a];
    }
#pragma unroll
    for (int mi = 0; mi < 8; ++mi) {
#pragma unroll
        for (int rg = 0; rg < 4; ++rg) {
            float s = 0.0f;
#pragma unroll
            for (int ni = 0; ni < 4; ++ni) {
                float x = acc[mi][ni][rg] + dd[ni];
                float e2 = __expf(2.0f * x);
                float th = 1.0f - 2.0f * __builtin_amdgcn_rcpf(e2 + 1.0f);
                s += vv[ni] * th;
            }
            s += __shfl_xor(s, 8);
            s += __shfl_xor(s, 4);
            s += __shfl_xor(s, 2);
            s += __shfl_xor(s, 1);
            if (col == 0)
                atomicAdd(&s_acc[wm * 128 + mi * 16 + quad * 4 + rg], s);
        }
    }
    __syncthreads();
    if (tid < 256)
        atomicAdd(&scores[(size_t)n * TT + t0 + tid], s_acc[tid]);
}

// ---------------- fused softmax + weights write + ctx accumulate -------------
// 512 blocks: n(32) x ec(4) x ts(4). Each block recomputes its row's masked
// (m, sum) from scores (cheap, L2-hot); ec==0 blocks write the weights chunk;
// ctx partial accumulated only over t < len (masked t contribute exactly 0).
__global__ __launch_bounds__(256) void k_ctxsm(const _Float16* __restrict__ h_enc16,
                                               const float* __restrict__ sc,
                                               const int* __restrict__ lens,
                                               float* __restrict__ wts,
                                               float* __restrict__ ctx) {
    __shared__ float red[4], red2[4];
    __shared__ float racc[256][8];
    const int b = blockIdx.x;
    const int n = b >> 4, ec = (b >> 2) & 3, ts = b & 3;
    const int tid = threadIdx.x;
    const int len = lens[n];
    const float* srow = sc + (size_t)n * TT;

    float sv[8];
    float m = -3.0e38f;
#pragma unroll
    for (int i = 0; i < 8; ++i) {
        int t = tid + i * 256;
        float s = srow[t];
        s = (t < len) ? s : -1.0e10f;
        sv[i] = s;
        m = fmaxf(m, s);
    }
    for (int off = 1; off <= 32; off <<= 1) m = fmaxf(m, __shfl_xor(m, off));
    if ((tid & 63) == 0) red[tid >> 6] = m;
    __syncthreads();
    m = fmaxf(fmaxf(red[0], red[1]), fmaxf(red[2], red[3]));
    float sum = 0.f;
#pragma unroll
    for (int i = 0; i < 8; ++i) sum += __expf(sv[i] - m);
    for (int off = 1; off <= 32; off <<= 1) sum += __shfl_xor(sum, off);
    if ((tid & 63) == 0) red2[tid >> 6] = sum;
    __syncthreads();
    sum = red2[0] + red2[1] + red2[2] + red2[3];
    const float rinv = 1.0f / sum;

    // weights for this ts-chunk, written once (by ec==0 blocks)
    if (ec == 0) {
#pragma unroll
        for (int j = 0; j < 2; ++j) {
            int t = ts * 512 + j * 256 + tid;
            float s = srow[t];
            s = (t < len) ? s : -1.0e10f;
            wts[(size_t)n * TT + t] = __expf(s - m) * rinv;   // masked -> 0.f
        }
    }

    // ctx partial over t in [ts*512, min(ts*512+512, len))
    if (ts * 512 < len) {
        const int tend = min(ts * 512 + 512, len);
        const int q = tid & 31, tg = tid >> 5;
        const int e = ec * 256 + q * 8;
        float acc[8];
#pragma unroll
        for (int j = 0; j < 8; ++j) acc[j] = 0.f;
        for (int t = ts * 512 + tg; t < tend; t += 8) {
            float w = __expf(srow[t] - m) * rinv;
            uint4 raw = *reinterpret_cast<const uint4*>(
                h_enc16 + ((size_t)(n * TT + t)) * HS + e);
            const _Float16* hp = reinterpret_cast<const _Float16*>(&raw);
#pragma unroll
            for (int j = 0; j < 8; ++j) acc[j] += w * (float)hp[j];
        }
#pragma unroll
        for (int j = 0; j < 8; ++j) racc[tid][j] = acc[j];
        __syncthreads();
        if (tid < 32) {
            float s2[8];
#pragma unroll
            for (int j = 0; j < 8; ++j) s2[j] = racc[tid][j];
            for (int g = 1; g < 8; ++g)
#pragma unroll
                for (int j = 0; j < 8; ++j) s2[j] += racc[g * 32 + tid][j];
            float* dst = ctx + (size_t)n * HS + ec * 256 + tid * 8;
#pragma unroll
            for (int j = 0; j < 8; ++j) atomicAdd(dst + j, s2[j]);
        }
    }
}

// ---------------- legacy kernels (mid-tier fallback if ws lacks sc room) -----
__global__ __launch_bounds__(256) void k_dproj(const float* __restrict__ h_dec,
                                               const float* __restrict__ W,
                                               const float* __restrict__ bias,
                                               float* __restrict__ dproj) {
    int wid = blockIdx.x * 4 + (threadIdx.x >> 6);
    int lane = threadIdx.x & 63;
    int n = wid >> 10, a = wid & 1023;
    const float4* hd = reinterpret_cast<const float4*>(h_dec + (size_t)n * HS);
    const float4* wr = reinterpret_cast<const float4*>(W + (size_t)a * 2048);
    float s = 0.f;
#pragma unroll
    for (int i = 0; i < 4; ++i) {
        float4 h = hd[lane + i * 64];
        float4 w = wr[lane + i * 64];
        s += h.x * w.x + h.y * w.y + h.z * w.z + h.w * w.w;
    }
    for (int off = 32; off; off >>= 1) s += __shfl_xor(s, off);
    if (lane == 0) dproj[wid] = bias[a] + s;
}

__global__ __launch_bounds__(256) void k_cvtW(const float* __restrict__ W,
                                              _Float16* __restrict__ We16) {
    int idx4 = (blockIdx.x * 256 + threadIdx.x) * 4;
    int a = idx4 >> 10;
    int e = idx4 & 1023;
    float4 f = *reinterpret_cast<const float4*>(W + (size_t)a * 2048 + 1024 + e);
    _Float16 h0 = (_Float16)f.x, h1 = (_Float16)f.y, h2 = (_Float16)f.z, h3 = (_Float16)f.w;
    ushort4 p;
    p.x = *(unsigned short*)&h0; p.y = *(unsigned short*)&h1;
    p.z = *(unsigned short*)&h2; p.w = *(unsigned short*)&h3;
    *reinterpret_cast<ushort4*>(We16 + idx4) = p;
}

__global__ __launch_bounds__(256) void k_cvtA(const float* __restrict__ h_enc,
                                              _Float16* __restrict__ h_enc16) {
    size_t idx = ((size_t)blockIdx.x * 256 + threadIdx.x) * 16;
    const float4* g = reinterpret_cast<const float4*>(h_enc + idx);
    _Float16 h[16];
#pragma unroll
    for (int i = 0; i < 4; ++i) {
        float4 f = g[i];
        h[i * 4 + 0] = (_Float16)f.x; h[i * 4 + 1] = (_Float16)f.y;
        h[i * 4 + 2] = (_Float16)f.z; h[i * 4 + 3] = (_Float16)f.w;
    }
    *reinterpret_cast<uint4*>(h_enc16 + idx)     = *reinterpret_cast<uint4*>(&h[0]);
    *reinterpret_cast<uint4*>(h_enc16 + idx + 8) = *reinterpret_cast<uint4*>(&h[8]);
}

__global__ __launch_bounds__(256) void k_softmax(float* __restrict__ wout,
                                                 const int* __restrict__ lens) {
    __shared__ float red[4];
    __shared__ float red2[4];
    int n = blockIdx.x, tid = threadIdx.x;
    int len = lens[n];
    float* row = wout + (size_t)n * TT;
    float sv[8];
    float m = -3.0e38f;
#pragma unroll
    for (int i = 0; i < 8; ++i) {
        int t = tid + i * 256;
        float s = row[t];
        s = (t < len) ? s : -1.0e10f;
        sv[i] = s;
        m = fmaxf(m, s);
    }
    for (int off = 1; off <= 32; off <<= 1) m = fmaxf(m, __shfl_xor(m, off));
    if ((tid & 63) == 0) red[tid >> 6] = m;
    __syncthreads();
    m = fmaxf(fmaxf(red[0], red[1]), fmaxf(red[2], red[3]));
    float sum = 0.f, es[8];
#pragma unroll
    for (int i = 0; i < 8; ++i) { es[i] = __expf(sv[i] - m); sum += es[i]; }
    for (int off = 1; off <= 32; off <<= 1) sum += __shfl_xor(sum, off);
    if ((tid & 63) == 0) red2[tid >> 6] = sum;
    __syncthreads();
    sum = red2[0] + red2[1] + red2[2] + red2[3];
    float rinv = 1.0f / sum;
#pragma unroll
    for (int i = 0; i < 8; ++i) row[tid + i * 256] = es[i] * rinv;
}

__global__ __launch_bounds__(256) void k_ctx(const _Float16* __restrict__ h_enc16,
                                             const float* __restrict__ wts,
                                             float* __restrict__ ctx) {
    __shared__ float red[256][8];
    int b = blockIdx.x;
    int n  = b >> 4;
    int ec = (b >> 2) & 3;
    int ts = b & 3;
    int tid = threadIdx.x;
    int q = tid & 31, tg = tid >> 5;
    int e = ec * 256 + q * 8;
    float acc[8];
#pragma unroll
    for (int j = 0; j < 8; ++j) acc[j] = 0.f;
    const float* wrow = wts + (size_t)n * TT;
    for (int t = ts * 512 + tg; t < ts * 512 + 512; t += 8) {
        float w = wrow[t];
        uint4 raw = *reinterpret_cast<const uint4*>(
            h_enc16 + ((size_t)(n * TT + t)) * HS + e);
        const _Float16* hp = reinterpret_cast<const _Float16*>(&raw);
#pragma unroll
        for (int j = 0; j < 8; ++j) acc[j] += w * (float)hp[j];
    }
#pragma unroll
    for (int j = 0; j < 8; ++j) red[tid][j] = acc[j];
    __syncthreads();
    if (tid < 32) {
        float s[8];
#pragma unroll
        for (int j = 0; j < 8; ++j) s[j] = red[tid][j];
        for (int g = 1; g < 8; ++g)
#pragma unroll
            for (int j = 0; j < 8; ++j) s[j] += red[g * 32 + tid][j];
        float* dst = ctx + (size_t)n * HS + ec * 256 + tid * 8;
#pragma unroll
        for (int j = 0; j < 8; ++j) atomicAdd(dst + j, s[j]);
    }
}

// ---------- slow-but-correct fallback (only if ws is tiny; unexpected) -------
__global__ __launch_bounds__(256) void k_score_naive(const float* __restrict__ h_enc,
                                                     const float* __restrict__ W,
                                                     const float* __restrict__ dproj,
                                                     const float* __restrict__ v,
                                                     float* __restrict__ scores) {
    int gw = blockIdx.x * 4 + (threadIdx.x >> 6);
    int lane = threadIdx.x & 63;
    int n = gw >> 11, t = gw & 2047;
    const float4* he = reinterpret_cast<const float4*>(h_enc + ((size_t)(n * TT + t)) * HS);
    float4 hv[4];
#pragma unroll
    for (int i = 0; i < 4; ++i) hv[i] = he[lane + i * 64];
    float s = 0.f;
    for (int a = 0; a < 1024; ++a) {
        const float4* wr = reinterpret_cast<const float4*>(W + (size_t)a * 2048 + 1024);
        float d = 0.f;
#pragma unroll
        for (int i = 0; i < 4; ++i) {
            float4 wv = wr[lane + i * 64];
            d += hv[i].x * wv.x + hv[i].y * wv.y + hv[i].z * wv.z + hv[i].w * wv.w;
        }
        for (int off = 32; off; off >>= 1) d += __shfl_xor(d, off);
        s += v[a] * tanhf(d + dproj[n * HS + a]);
    }
    if (lane == 0) scores[(size_t)n * TT + t] = s;
}

__global__ __launch_bounds__(256) void k_ctx_naive(const float* __restrict__ h_enc,
                                                   const float* __restrict__ wts,
                                                   float* __restrict__ ctx) {
    int n = blockIdx.x;
    int e = threadIdx.x * 4;
    float4 a = make_float4(0.f, 0.f, 0.f, 0.f);
    const float* wrow = wts + (size_t)n * TT;
    for (int t = 0; t < TT; ++t) {
        float w = wrow[t];
        float4 h = *reinterpret_cast<const float4*>(h_enc + ((size_t)(n * TT + t)) * HS + e);
        a.x += w * h.x; a.y += w * h.y; a.z += w * h.z; a.w += w * h.w;
    }
    *reinterpret_cast<float4*>(ctx + (size_t)n * HS + e) = a;
}

extern "C" void kernel_launch(void* const* d_in, const int* in_sizes, int n_in,
                              void* d_out, int out_size, void* d_ws, size_t ws_size,
                              hipStream_t stream) {
    const float* h_dec    = (const float*)d_in[0];
    const float* h_enc    = (const float*)d_in[1];
    const int*   src_lens = (const int*)d_in[2];
    const float* W = (const float*)d_in[3];
    const float* b = (const float*)d_in[4];
    const float* v = (const float*)d_in[5];

    float* out = (float*)d_out;
    float* ctx = out;                 // 32*1024
    float* wts = out + 32 * 1024;     // 32*2048

    float*    dproj   = (float*)d_ws;                                  // 128 KB
    _Float16* We16    = (_Float16*)((char*)d_ws + 131072);             // 2 MB
    _Float16* h_enc16 = (_Float16*)((char*)d_ws + 131072 + 2097152);   // 128 MB
    float*    sc      = (float*)((char*)d_ws + 131072 + 2097152 +
                                 (size_t)32 * TT * HS * 2);            // 256 KB
    const size_t need_mid = 131072 + 2097152 + (size_t)32 * TT * HS * 2;
    const size_t need_new = need_mid + (size_t)32 * TT * sizeof(float);

    if (ws_size >= need_new) {
        // 3-dispatch path: pre (cvtA+dproj+cvtW+zeroing) -> score -> ctx+softmax
        k_pre   <<<25696, 256, 0, stream>>>(h_enc, h_enc16, h_dec, W, b, src_lens,
                                            dproj, We16, sc, ctx);
        k_score8<<<1024, 512, 0, stream>>>(h_enc16, We16, dproj, v, src_lens, sc);
        k_ctxsm <<<512, 256, 0, stream>>>(h_enc16, sc, src_lens, wts, ctx);
    } else if (ws_size >= need_mid) {
        // legacy path, scores live in out-wts
        k_dproj<<<8192, 256, 0, stream>>>(h_dec, W, b, dproj);
        (void)hipMemsetAsync(ctx, 0, 32 * 1024 * sizeof(float), stream);
        (void)hipMemsetAsync(wts, 0, (size_t)32 * TT * sizeof(float), stream);
        k_cvtW <<<1024, 256, 0, stream>>>(W, We16);
        k_cvtA <<<16384, 256, 0, stream>>>(h_enc, h_enc16);
        k_score8<<<1024, 512, 0, stream>>>(h_enc16, We16, dproj, v, src_lens, wts);
        k_softmax<<<32, 256, 0, stream>>>(wts, src_lens);
        k_ctx  <<<512, 256, 0, stream>>>(h_enc16, wts, ctx);
    } else {
        k_dproj<<<8192, 256, 0, stream>>>(h_dec, W, b, dproj);
        k_score_naive<<<16384, 256, 0, stream>>>(h_enc, W, dproj, v, wts);
        k_softmax<<<32, 256, 0, stream>>>(wts, src_lens);
        k_ctx_naive<<<32, 256, 0, stream>>>(h_enc, wts, ctx);
    }
}